// Round 3
// baseline (181.352 us; speedup 1.0000x reference)
//
#include <hip/hip_runtime.h>

// Problem constants (reference: B=8, T=24, N=1024, D=64, W=2) — all f32 I/O.
#define BB 8
#define TT 24
#define NN 1024
#define DD 64
#define WW 2
#define MROWS (BB * TT * NN)   // 196608 rows of D=64
#define NTILES (MROWS / 16)    // 12288 16-row tiles

typedef float  f32x4  __attribute__((ext_vector_type(4)));  // 16B vector load / MFMA C-D frag
typedef __bf16 bf16x8 __attribute__((ext_vector_type(8)));  // MFMA A/B operand

__global__ __launch_bounds__(256, 4) void stgcn_kernel(
    const float* __restrict__ x,     // [B,T,N,D] f32
    const float* __restrict__ W1,    // [D,D]
    const float* __restrict__ b1,    // [D]
    const float* __restrict__ W2,    // [D,D]
    const float* __restrict__ b2,    // [D]
    const float* __restrict__ gamma, // [D]
    const float* __restrict__ beta,  // [D]
    const float* __restrict__ adj,   // [N, N*W]
    float* __restrict__ out)         // [B,T,N,D]
{
    const int lane = threadIdx.x & 63;
    const int wv   = threadIdx.x >> 6;
    const int m16  = lane & 15;
    const int quad = lane >> 4;
    const int e4   = quad * 4;       // lane's 4-wide e-subgroup base within each 16-col group

    // ---- Stage weight fragments in LDS, once per BLOCK (shared by 4 waves) ----
    // Fragment group g = mat*8 + et*2 + ks (16 groups); slot l = quad*16 + m16 holds
    // bf16x8 of W[e=et*16+m16][ks*32+quad*8 .. +7].  16 KB total.
    __shared__ bf16x8 wlds[16][64];
    for (int s = threadIdx.x; s < 16 * 64; s += 256) {
        const int g  = s >> 6, l = s & 63;
        const int mat = g >> 3, et = (g >> 1) & 3, ks = g & 1;
        const int ms = l & 15, qs = l >> 4;
        const float* src = (mat ? W2 : W1) + (et * 16 + ms) * DD + ks * 32 + qs * 8;
        const f32x4 a = *(const f32x4*)(src);
        const f32x4 b = *(const f32x4*)(src + 4);
        bf16x8 f;
#pragma unroll
        for (int j = 0; j < 4; ++j) { f[j] = (__bf16)a[j]; f[j + 4] = (__bf16)b[j]; }
        wlds[g][l] = f;
    }
    __syncthreads();

    // ---- Adjacency diag coefficients: invariant across this wave's tiles ----
    // grid = 1024 blocks * 4 waves = 4096 waves; tile stride * 16 rows = 65536 ≡ 0 (mod NN),
    // so n = (tile*16 % NN) + m16 is the same for all tiles of this wave. Hoist the gather.
    const int nWaves = (gridDim.x * blockDim.x) >> 6;
    const int tile0  = blockIdx.x * (blockDim.x >> 6) + wv;
    const int n      = ((tile0 * 16) % NN) + m16;
    const float c0 = adj[(size_t)n * (NN * WW) + n];        // weight on x[t-1]
    const float c1 = adj[(size_t)n * (NN * WW) + NN + n];   // weight on x[t]
    const float cb = c0 + c1;                                // bias scale (own row's coeff)

    for (int tile = tile0; tile < NTILES; tile += nWaves) {
        const int r0 = tile * 16;            // 16 rows share (b,t); n consecutive
        const int t  = (r0 / NN) % TT;       // wave-uniform

        const float* xr = x + (size_t)(r0 + m16) * DD;

        // B-operand source: row m16, cols {quad*8..+7, 32+quad*8..+7}
        const f32x4 c00 = *(const f32x4*)(xr + quad * 8);
        const f32x4 c01 = *(const f32x4*)(xr + quad * 8 + 4);
        const f32x4 c10 = *(const f32x4*)(xr + 32 + quad * 8);
        const f32x4 c11 = *(const f32x4*)(xr + 36 + quad * 8);

        // Epilogue x: row m16, cols et*16 + e4 + {0..3} — vectorized, issued early
        f32x4 xe[4];
#pragma unroll
        for (int et = 0; et < 4; ++et)
            xe[et] = *(const f32x4*)(xr + et * 16 + e4);

        f32x4 p00 = {0.f,0.f,0.f,0.f}, p01 = {0.f,0.f,0.f,0.f};
        f32x4 p10 = {0.f,0.f,0.f,0.f}, p11 = {0.f,0.f,0.f,0.f};
        if (t > 0) {                          // wave-uniform branch
            const float* xq = xr - NN * DD;
            p00 = *(const f32x4*)(xq + quad * 8);
            p01 = *(const f32x4*)(xq + quad * 8 + 4);
            p10 = *(const f32x4*)(xq + 32 + quad * 8);
            p11 = *(const f32x4*)(xq + 36 + quad * 8);
        }

        // xbar = c0*x_prev + c1*x_cur -> bf16 B-operand fragments
        bf16x8 X0, X1;
#pragma unroll
        for (int j = 0; j < 4; ++j) {
            X0[j]     = (__bf16)(c0 * p00[j] + c1 * c00[j]);
            X0[j + 4] = (__bf16)(c0 * p01[j] + c1 * c01[j]);
            X1[j]     = (__bf16)(c0 * p10[j] + c1 * c10[j]);
            X1[j + 4] = (__bf16)(c0 * p11[j] + c1 * c11[j]);
        }

        // ---- MFMA (operands swapped): lane m16 owns row m16 of the output ----
        // acc{1,2}[et][r] = h[row=m16][e = et*16 + e4 + r]
        f32x4 acc1[4], acc2[4];
#pragma unroll
        for (int et = 0; et < 4; ++et) {
            acc1[et] = (f32x4){0.f, 0.f, 0.f, 0.f};
            acc2[et] = (f32x4){0.f, 0.f, 0.f, 0.f};
        }
#pragma unroll
        for (int et = 0; et < 4; ++et) {
            const bf16x8 w10 = wlds[et * 2 + 0][lane];      // W1, ks=0
            const bf16x8 w11 = wlds[et * 2 + 1][lane];      // W1, ks=1
            const bf16x8 w20 = wlds[8 + et * 2 + 0][lane];  // W2, ks=0
            const bf16x8 w21 = wlds[8 + et * 2 + 1][lane];  // W2, ks=1
            acc1[et] = __builtin_amdgcn_mfma_f32_16x16x32_bf16(w10, X0, acc1[et], 0, 0, 0);
            acc1[et] = __builtin_amdgcn_mfma_f32_16x16x32_bf16(w11, X1, acc1[et], 0, 0, 0);
            acc2[et] = __builtin_amdgcn_mfma_f32_16x16x32_bf16(w20, X0, acc2[et], 0, 0, 0);
            acc2[et] = __builtin_amdgcn_mfma_f32_16x16x32_bf16(w21, X1, acc2[et], 0, 0, 0);
        }

        // ---- Epilogue: bias, relu(a1*a2)+a1, +x, LayerNorm — all row-local ----
        float s = 0.f, s2 = 0.f;
        f32x4 z[4];
#pragma unroll
        for (int et = 0; et < 4; ++et) {
            const f32x4 b1v = *(const f32x4*)(b1 + et * 16 + e4);  // L1-hot transient
            const f32x4 b2v = *(const f32x4*)(b2 + et * 16 + e4);
#pragma unroll
            for (int r = 0; r < 4; ++r) {
                const float A1v = acc1[et][r] + cb * b1v[r];
                const float A2v = acc2[et][r] + cb * b2v[r];
                const float p   = A1v * A2v;
                const float full = (p > 0.f ? p : 0.f) + A1v;
                const float zz = full + xe[et][r];
                z[et][r] = zz;
                s  += zz;
                s2 += zz * zz;
            }
        }

        // Row reduction across the 4 quads holding row m16
        s  += __shfl_xor(s, 16, 64);
        s2 += __shfl_xor(s2, 16, 64);
        s  += __shfl_xor(s, 32, 64);
        s2 += __shfl_xor(s2, 32, 64);

        const float mu  = s * (1.f / 64.f);
        const float var = s2 * (1.f / 64.f) - mu * mu;
        const float rs  = rsqrtf(var + 1e-5f);

        float* orow = out + (size_t)(r0 + m16) * DD;
#pragma unroll
        for (int et = 0; et < 4; ++et) {
            const f32x4 gvv = *(const f32x4*)(gamma + et * 16 + e4);
            const f32x4 bev = *(const f32x4*)(beta  + et * 16 + e4);
            f32x4 o;
#pragma unroll
            for (int r = 0; r < 4; ++r)
                o[r] = (z[et][r] - mu) * rs * gvv[r] + bev[r];
            *(f32x4*)(orow + et * 16 + e4) = o;   // 16B coalesced store
        }
    }
}

extern "C" void kernel_launch(void* const* d_in, const int* in_sizes, int n_in,
                              void* d_out, int out_size, void* d_ws, size_t ws_size,
                              hipStream_t stream) {
    const float* x     = (const float*)d_in[0];
    const float* W1    = (const float*)d_in[1];
    const float* b1    = (const float*)d_in[2];
    const float* W2    = (const float*)d_in[3];
    const float* b2    = (const float*)d_in[4];
    const float* gamma = (const float*)d_in[5];
    const float* beta  = (const float*)d_in[6];
    const float* adj   = (const float*)d_in[7];
    float* out = (float*)d_out;

    // 1024 blocks * 4 waves = 4096 waves, exactly 3 tiles each (12288 tiles);
    // 4 blocks/CU resident (VGPR-capped) -> zero tail, full packing.
    dim3 grid(1024), block(256);
    hipLaunchKernelGGL(stgcn_kernel, grid, block, 0, stream,
                       x, W1, b1, W2, b2, gamma, beta, adj, out);
}

// Round 4
// 131.244 us; speedup vs baseline: 1.3818x; 1.3818x over previous
//
#include <hip/hip_runtime.h>

// Problem constants (reference: B=8, T=24, N=1024, D=64, W=2) — all f32 I/O.
#define BB 8
#define TT 24
#define NN 1024
#define DD 64
#define WW 2
#define MROWS (BB * TT * NN)   // 196608 rows of D=64
#define NTILES (MROWS / 16)    // 12288 16-row tiles
#define NWAVES 3072            // grid 768 x 4 waves; 12288/3072 = exactly 4 tiles/wave
#define KTILES 4
#define ROWSTRIDE ((size_t)NWAVES * 16 * DD)  // floats between a wave's consecutive tiles

typedef float  f32x4  __attribute__((ext_vector_type(4)));  // 16B vector load / MFMA C-D frag
typedef __bf16 bf16x8 __attribute__((ext_vector_type(8)));  // MFMA A/B operand

__global__ __launch_bounds__(256) void stgcn_kernel(
    const float* __restrict__ x,     // [B,T,N,D] f32
    const float* __restrict__ W1,    // [D,D]
    const float* __restrict__ b1,    // [D]
    const float* __restrict__ W2,    // [D,D]
    const float* __restrict__ b2,    // [D]
    const float* __restrict__ gamma, // [D]
    const float* __restrict__ beta,  // [D]
    const float* __restrict__ adj,   // [N, N*W]
    float* __restrict__ out)         // [B,T,N,D]
{
    const int lane = threadIdx.x & 63;
    const int wv   = threadIdx.x >> 6;
    const int m16  = lane & 15;
    const int quad = lane >> 4;
    const int e4   = quad * 4;       // lane's 4-wide e-subgroup base within each 16-col group

    // ---- Stage weight fragments in LDS, once per BLOCK (shared by 4 waves) ----
    // group g = mat*8 + et*2 + ks; slot l = quad*16+m16 holds bf16x8 of
    // W[e=et*16+m16][ks*32+quad*8 .. +7].  16 KB total.
    __shared__ bf16x8 wlds[16][64];
    for (int s = threadIdx.x; s < 16 * 64; s += 256) {
        const int g  = s >> 6, l = s & 63;
        const int mat = g >> 3, et = (g >> 1) & 3, ks = g & 1;
        const int ms = l & 15, qs = l >> 4;
        const float* src = (mat ? W2 : W1) + (et * 16 + ms) * DD + ks * 32 + qs * 8;
        const f32x4 a = *(const f32x4*)(src);
        const f32x4 b = *(const f32x4*)(src + 4);
        bf16x8 f;
#pragma unroll
        for (int j = 0; j < 4; ++j) { f[j] = (__bf16)a[j]; f[j + 4] = (__bf16)b[j]; }
        wlds[g][l] = f;
    }
    __syncthreads();

    // ---- Wave-invariant setup: this wave's 4 tiles are tile0 + k*3072 ----
    // stride in rows = 49152 ≡ 0 (mod NN) and 49152/NN = 48 ≡ 0 (mod TT),
    // so node set n AND time index t are identical for all 4 tiles (only b varies).
    const int tile0 = blockIdx.x * 4 + wv;         // [0, 3072)
    const int rbase = tile0 * 16;
    const int t     = (rbase / NN) % TT;           // wave-uniform, k-invariant
    const int n     = (rbase % NN) + m16;          // this lane's node, k-invariant

    const float c0 = adj[(size_t)n * (NN * WW) + n];        // weight on x[t-1]
    const float c1 = adj[(size_t)n * (NN * WW) + NN + n];   // weight on x[t]
    const float cb = c0 + c1;                       // bias scale (padded rows still add bias)
    const float c0d = (t > 0) ? c0 : 0.f;           // data blend coeff (zero-padded at t=0)
    const ptrdiff_t prevOff = (t > 0) ? -(ptrdiff_t)(NN * DD) : 0;  // clamp: reads cur row *0

    const float* xr0 = x + (size_t)(rbase + m16) * DD;

    struct CP { f32x4 c[4], p[4]; };
    auto loadCP = [&](int k) {
        const float* xr = xr0 + (size_t)k * ROWSTRIDE;
        const float* xq = xr + prevOff;
        CP r;
        r.c[0] = *(const f32x4*)(xr + quad * 8);
        r.c[1] = *(const f32x4*)(xr + quad * 8 + 4);
        r.c[2] = *(const f32x4*)(xr + 32 + quad * 8);
        r.c[3] = *(const f32x4*)(xr + 36 + quad * 8);
        r.p[0] = *(const f32x4*)(xq + quad * 8);
        r.p[1] = *(const f32x4*)(xq + quad * 8 + 4);
        r.p[2] = *(const f32x4*)(xq + 32 + quad * 8);
        r.p[3] = *(const f32x4*)(xq + 36 + quad * 8);
        return r;
    };

    CP cur = loadCP(0);                             // prologue: tile 0 x-rows in flight

#pragma unroll
    for (int k = 0; k < KTILES; ++k) {
        // ---- prefetch next tile's x-rows BEFORE consuming this tile's ----
        CP nxt;
        if (k + 1 < KTILES) nxt = loadCP(k + 1);

        const float* xr = xr0 + (size_t)k * ROWSTRIDE;

        // epilogue x: row m16, cols et*16+e4+{0..3} — L1-hot (same 256B row), issue early
        f32x4 xe[4];
#pragma unroll
        for (int et = 0; et < 4; ++et)
            xe[et] = *(const f32x4*)(xr + et * 16 + e4);

        // ---- blend xbar = c0d*x_prev + c1*x_cur -> bf16 B-operand fragments ----
        bf16x8 X0, X1;
#pragma unroll
        for (int j = 0; j < 4; ++j) {
            X0[j]     = (__bf16)(c0d * cur.p[0][j] + c1 * cur.c[0][j]);
            X0[j + 4] = (__bf16)(c0d * cur.p[1][j] + c1 * cur.c[1][j]);
            X1[j]     = (__bf16)(c0d * cur.p[2][j] + c1 * cur.c[2][j]);
            X1[j + 4] = (__bf16)(c0d * cur.p[3][j] + c1 * cur.c[3][j]);
        }

        // ---- MFMA (operands swapped): lane m16 owns output row m16 ----
        // acc{1,2}[et][r] = h[row=m16][e = et*16 + e4 + r]
        f32x4 acc1[4], acc2[4];
#pragma unroll
        for (int et = 0; et < 4; ++et) {
            acc1[et] = (f32x4){0.f, 0.f, 0.f, 0.f};
            acc2[et] = (f32x4){0.f, 0.f, 0.f, 0.f};
        }
#pragma unroll
        for (int et = 0; et < 4; ++et) {
            const bf16x8 w10 = wlds[et * 2 + 0][lane];      // W1, ks=0
            const bf16x8 w11 = wlds[et * 2 + 1][lane];      // W1, ks=1
            const bf16x8 w20 = wlds[8 + et * 2 + 0][lane];  // W2, ks=0
            const bf16x8 w21 = wlds[8 + et * 2 + 1][lane];  // W2, ks=1
            acc1[et] = __builtin_amdgcn_mfma_f32_16x16x32_bf16(w10, X0, acc1[et], 0, 0, 0);
            acc1[et] = __builtin_amdgcn_mfma_f32_16x16x32_bf16(w11, X1, acc1[et], 0, 0, 0);
            acc2[et] = __builtin_amdgcn_mfma_f32_16x16x32_bf16(w20, X0, acc2[et], 0, 0, 0);
            acc2[et] = __builtin_amdgcn_mfma_f32_16x16x32_bf16(w21, X1, acc2[et], 0, 0, 0);
        }

        // ---- Epilogue: bias, relu(a1*a2)+a1, +x, LayerNorm — all row-local ----
        float s = 0.f, s2 = 0.f;
        f32x4 z[4];
#pragma unroll
        for (int et = 0; et < 4; ++et) {
            const f32x4 b1v = *(const f32x4*)(b1 + et * 16 + e4);  // L1-hot transient
            const f32x4 b2v = *(const f32x4*)(b2 + et * 16 + e4);
#pragma unroll
            for (int r = 0; r < 4; ++r) {
                const float A1v = acc1[et][r] + cb * b1v[r];
                const float A2v = acc2[et][r] + cb * b2v[r];
                const float p   = A1v * A2v;
                const float full = (p > 0.f ? p : 0.f) + A1v;
                const float zz = full + xe[et][r];
                z[et][r] = zz;
                s  += zz;
                s2 += zz * zz;
            }
        }

        // Row reduction across the 4 quads holding row m16
        s  += __shfl_xor(s, 16, 64);
        s2 += __shfl_xor(s2, 16, 64);
        s  += __shfl_xor(s, 32, 64);
        s2 += __shfl_xor(s2, 32, 64);

        const float mu  = s * (1.f / 64.f);
        const float var = s2 * (1.f / 64.f) - mu * mu;
        const float rs  = rsqrtf(var + 1e-5f);

        float* orow = out + (size_t)(rbase + m16) * DD + (size_t)k * ROWSTRIDE;
#pragma unroll
        for (int et = 0; et < 4; ++et) {
            const f32x4 gvv = *(const f32x4*)(gamma + et * 16 + e4);
            const f32x4 bev = *(const f32x4*)(beta  + et * 16 + e4);
            f32x4 o;
#pragma unroll
            for (int r = 0; r < 4; ++r)
                o[r] = (z[et][r] - mu) * rs * gvv[r] + bev[r];
            *(f32x4*)(orow + et * 16 + e4) = o;   // 16B coalesced store
        }

        if (k + 1 < KTILES) cur = nxt;
    }
}

extern "C" void kernel_launch(void* const* d_in, const int* in_sizes, int n_in,
                              void* d_out, int out_size, void* d_ws, size_t ws_size,
                              hipStream_t stream) {
    const float* x     = (const float*)d_in[0];
    const float* W1    = (const float*)d_in[1];
    const float* b1    = (const float*)d_in[2];
    const float* W2    = (const float*)d_in[3];
    const float* b2    = (const float*)d_in[4];
    const float* gamma = (const float*)d_in[5];
    const float* beta  = (const float*)d_in[6];
    const float* adj   = (const float*)d_in[7];
    float* out = (float*)d_out;

    // 768 blocks * 4 waves = 3072 waves, exactly 4 tiles each; 3 blocks/CU, zero tail.
    // NO min-occupancy launch bound: round 3 proved forcing VGPR<=64 causes scratch
    // spills (FETCH/WRITE exploded 3x). Let the allocator use ~120-150 regs.
    dim3 grid(768), block(256);
    hipLaunchKernelGGL(stgcn_kernel, grid, block, 0, stream,
                       x, W1, b1, W2, b2, gamma, beta, adj, out);
}

// Round 5
// 126.449 us; speedup vs baseline: 1.4342x; 1.0379x over previous
//
#include <hip/hip_runtime.h>

// Problem constants (reference: B=8, T=24, N=1024, D=64, W=2) — all f32 I/O.
#define BB 8
#define TT 24
#define NN 1024
#define DD 64
#define WW 2
// 12288 tiles = 8(b) x 24(t) x 64(nt). Wave owns (b, nt, tg): 3 consecutive t steps.
// 4096 waves = 1024 blocks x 4; exact cover, zero tail.

typedef float  f32x4  __attribute__((ext_vector_type(4)));  // 16B vector load / MFMA C-D frag
typedef __bf16 bf16x8 __attribute__((ext_vector_type(8)));  // MFMA A/B operand

#define LOADC(dst, ptr) do {                         \
    dst[0] = *(const f32x4*)((ptr) + q8);            \
    dst[1] = *(const f32x4*)((ptr) + q8 + 4);        \
    dst[2] = *(const f32x4*)((ptr) + 32 + q8);       \
    dst[3] = *(const f32x4*)((ptr) + 36 + q8);       \
} while (0)

// One time-step: PRV/CUR are f32x4[4] register buffers; DO_PREF literal 0/1.
#define STEP(K, PRV, CUR, DO_PREF, NXT, C0K) do {                                  \
    const size_t off = off0 + (size_t)(K) * (NN * DD);                             \
    const float* xr = x + off;                                                     \
    /* blend xbar = c0*x_prev + c1*x_cur -> bf16 B-fragments */                    \
    bf16x8 X0, X1;                                                                 \
    _Pragma("unroll")                                                              \
    for (int j = 0; j < 4; ++j) {                                                  \
        X0[j]     = (__bf16)((C0K) * PRV[0][j] + c1 * CUR[0][j]);                  \
        X0[j + 4] = (__bf16)((C0K) * PRV[1][j] + c1 * CUR[1][j]);                  \
        X1[j]     = (__bf16)((C0K) * PRV[2][j] + c1 * CUR[2][j]);                  \
        X1[j + 4] = (__bf16)((C0K) * PRV[3][j] + c1 * CUR[3][j]);                  \
    }                                                                              \
    /* prefetch next step's cur rows (its prev = CUR, already in regs) */          \
    if (DO_PREF) { LOADC(NXT, xr + NN * DD); }                                     \
    /* epilogue x re-read: same 256B row as CUR loads -> L1/L2 hot; issue early */ \
    f32x4 xe[4];                                                                   \
    _Pragma("unroll")                                                              \
    for (int et = 0; et < 4; ++et)                                                 \
        xe[et] = *(const f32x4*)(xr + et * 16 + e4);                               \
    /* MFMA (swapped operands): lane m16 owns output row m16 */                    \
    f32x4 acc1[4], acc2[4];                                                        \
    _Pragma("unroll")                                                              \
    for (int et = 0; et < 4; ++et) {                                               \
        acc1[et] = (f32x4){0.f, 0.f, 0.f, 0.f};                                    \
        acc2[et] = (f32x4){0.f, 0.f, 0.f, 0.f};                                    \
    }                                                                              \
    _Pragma("unroll")                                                              \
    for (int et = 0; et < 4; ++et) {                                               \
        const bf16x8 w10 = wlds[et * 2 + 0][lane];                                 \
        const bf16x8 w11 = wlds[et * 2 + 1][lane];                                 \
        const bf16x8 w20 = wlds[8 + et * 2 + 0][lane];                             \
        const bf16x8 w21 = wlds[8 + et * 2 + 1][lane];                             \
        acc1[et] = __builtin_amdgcn_mfma_f32_16x16x32_bf16(w10, X0, acc1[et], 0, 0, 0); \
        acc1[et] = __builtin_amdgcn_mfma_f32_16x16x32_bf16(w11, X1, acc1[et], 0, 0, 0); \
        acc2[et] = __builtin_amdgcn_mfma_f32_16x16x32_bf16(w20, X0, acc2[et], 0, 0, 0); \
        acc2[et] = __builtin_amdgcn_mfma_f32_16x16x32_bf16(w21, X1, acc2[et], 0, 0, 0); \
    }                                                                              \
    /* epilogue: bias, relu(a1*a2)+a1, +x, LayerNorm; z overwrites acc1 */         \
    float s = 0.f, s2 = 0.f;                                                       \
    _Pragma("unroll")                                                              \
    for (int et = 0; et < 4; ++et) {                                               \
        const f32x4 b1v = *(const f32x4*)(b1 + et * 16 + e4);                      \
        const f32x4 b2v = *(const f32x4*)(b2 + et * 16 + e4);                      \
        _Pragma("unroll")                                                          \
        for (int r = 0; r < 4; ++r) {                                              \
            const float A1v = acc1[et][r] + cb * b1v[r];                           \
            const float A2v = acc2[et][r] + cb * b2v[r];                           \
            const float p   = A1v * A2v;                                           \
            const float full = (p > 0.f ? p : 0.f) + A1v;                          \
            const float zz = full + xe[et][r];                                     \
            acc1[et][r] = zz;                                                      \
            s  += zz;                                                              \
            s2 += zz * zz;                                                         \
        }                                                                          \
    }                                                                              \
    s  += __shfl_xor(s, 16, 64);                                                   \
    s2 += __shfl_xor(s2, 16, 64);                                                  \
    s  += __shfl_xor(s, 32, 64);                                                   \
    s2 += __shfl_xor(s2, 32, 64);                                                  \
    const float mu  = s * (1.f / 64.f);                                            \
    const float var = s2 * (1.f / 64.f) - mu * mu;                                 \
    const float rs  = rsqrtf(var + 1e-5f);                                         \
    float* orow = out + off;                                                       \
    _Pragma("unroll")                                                              \
    for (int et = 0; et < 4; ++et) {                                               \
        const f32x4 gvv = *(const f32x4*)(gamma + et * 16 + e4);                   \
        const f32x4 bev = *(const f32x4*)(beta  + et * 16 + e4);                   \
        f32x4 o;                                                                   \
        _Pragma("unroll")                                                          \
        for (int r = 0; r < 4; ++r)                                                \
            o[r] = (acc1[et][r] - mu) * rs * gvv[r] + bev[r];                      \
        *(f32x4*)(orow + et * 16 + e4) = o;                                        \
    }                                                                              \
} while (0)

__global__ __launch_bounds__(256) void stgcn_kernel(
    const float* __restrict__ x,     // [B,T,N,D] f32
    const float* __restrict__ W1,    // [D,D]
    const float* __restrict__ b1,    // [D]
    const float* __restrict__ W2,    // [D,D]
    const float* __restrict__ b2,    // [D]
    const float* __restrict__ gamma, // [D]
    const float* __restrict__ beta,  // [D]
    const float* __restrict__ adj,   // [N, N*W]
    float* __restrict__ out)         // [B,T,N,D]
{
    const int lane = threadIdx.x & 63;
    const int wv   = threadIdx.x >> 6;
    const int m16  = lane & 15;
    const int quad = lane >> 4;
    const int e4   = quad * 4;
    const int q8   = quad * 8;

    // ---- Stage weight fragments in LDS, once per block (16 KB) ----
    __shared__ bf16x8 wlds[16][64];
    for (int s = threadIdx.x; s < 16 * 64; s += 256) {
        const int g  = s >> 6, l = s & 63;
        const int mat = g >> 3, et = (g >> 1) & 3, ks = g & 1;
        const int ms = l & 15, qs = l >> 4;
        const float* src = (mat ? W2 : W1) + (et * 16 + ms) * DD + ks * 32 + qs * 8;
        const f32x4 a = *(const f32x4*)(src);
        const f32x4 b = *(const f32x4*)(src + 4);
        bf16x8 f;
#pragma unroll
        for (int j = 0; j < 4; ++j) { f[j] = (__bf16)a[j]; f[j + 4] = (__bf16)b[j]; }
        wlds[g][l] = f;
    }
    __syncthreads();

    // ---- Wave -> (b, tg, nt): 3 consecutive time steps t = 3*tg + k ----
    const int wid = blockIdx.x * 4 + wv;   // [0, 4096)
    const int nt  = wid & 63;
    const int tg  = (wid >> 6) & 7;
    const int b   = wid >> 9;
    const int t0  = tg * 3;

    // adjacency diag coefficients (node n invariant across the wave's 3 steps)
    const int n = nt * 16 + m16;
    const float c0 = adj[(size_t)n * (NN * WW) + n];
    const float c1 = adj[(size_t)n * (NN * WW) + NN + n];
    const float cb = c0 + c1;   // bias coeff: cb even at t=0 (h(pad)=bias only)

    // this lane's row at step k=0
    const size_t off0 = ((size_t)(b * TT + t0) * NN + nt * 16 + m16) * DD;

    // ---- prologue: step-0 cur + prev (prev from memory only at a t-group seam) ----
    f32x4 cA[4], cB[4], cC[4], p0[4];
    LOADC(cA, x + off0);
    if (t0 > 0) {
        LOADC(p0, x + off0 - NN * DD);
    } else {
        p0[0] = p0[1] = p0[2] = p0[3] = (f32x4){0.f, 0.f, 0.f, 0.f};
    }
    const float c00 = (t0 > 0) ? c0 : 0.f;

    // ---- 3 steps, register-renamed prev chain: p0->cA->cB->cC ----
    STEP(0, p0, cA, 1, cB, c00);
    STEP(1, cA, cB, 1, cC, c0);
    STEP(2, cB, cC, 0, cC, c0);
}

extern "C" void kernel_launch(void* const* d_in, const int* in_sizes, int n_in,
                              void* d_out, int out_size, void* d_ws, size_t ws_size,
                              hipStream_t stream) {
    const float* x     = (const float*)d_in[0];
    const float* W1    = (const float*)d_in[1];
    const float* b1    = (const float*)d_in[2];
    const float* W2    = (const float*)d_in[3];
    const float* b2    = (const float*)d_in[4];
    const float* gamma = (const float*)d_in[5];
    const float* beta  = (const float*)d_in[6];
    const float* adj   = (const float*)d_in[7];
    float* out = (float*)d_out;

    // 1024 blocks x 4 waves = 4096 waves, 3 time-steps each = 12288 tiles exactly.
    // 4 blocks/CU resident (needs VGPR<=128 -- watch VGPR_Count!), zero tail.
    dim3 grid(1024), block(256);
    hipLaunchKernelGGL(stgcn_kernel, grid, block, 0, stream,
                       x, W1, b1, W2, b2, gamma, beta, adj, out);
}